// Round 7
// baseline (309.820 us; speedup 1.0000x reference)
//
#include <hip/hip_runtime.h>
#include <math.h>

#define PATTERNS 6
#define ITERS 50
#define LAMBDA_ 100.0f
// 1/(sqrt(2)*SIGMA), SIGMA=1.5
#define CST 0.47140452079103173f

// fused 3-sum xor-swizzle reduction within 8-lane groups:
// 3 independent swizzles in flight per step -> one latency wait amortized over 3 sums.
#define SWZ(v, pat) __int_as_float(__builtin_amdgcn_ds_swizzle(__float_as_int(v), pat))
#define RED3STEP(a, b, c, pat) { \
    float ta_ = SWZ(a, pat), tb_ = SWZ(b, pat), tc_ = SWZ(c, pat); \
    a += ta_; b += tb_; c += tc_; }
#define RED3(a, b, c) \
    RED3STEP(a, b, c, 0x041F) \
    RED3STEP(a, b, c, 0x081F) \
    RED3STEP(a, b, c, 0x101F)

#define PAIRS(X) X(0) X(1) X(2) X(3) X(4) X(5) X(6) X(7) \
                 X(8) X(9) X(10) X(11) X(12) X(13) X(14) X(15)

// 8 lanes per job: lane `sub` owns rows 2*sub, 2*sub+1 (32 px).
// Pure-scalar explicit registers: 64 floats state (s+g), no gg hoist, no ext-vector
// types -> fits arch VGPRs at 4 waves/SIMD, no AccVGPR copy traffic.
__global__ __launch_bounds__(256, 4) void intensity_kernel(
    const float* __restrict__ params,
    const float* __restrict__ data,
    float* __restrict__ out,
    int njobs)
{
    const int tid = blockIdx.x * 256 + threadIdx.x;
    const int job = tid >> 3;
    const int sub = tid & 7;
    if (job >= njobs) return;
    const int spot = job / PATTERNS;

    const float x = params[spot * 5 + 0];
    const float y = params[spot * 5 + 1];
    float I = params[spot * 5 + 4] * (1.0f / PATTERNS);
    float bg = 0.0f;

#define DECLV(k) float ga##k, gb##k, sa##k, sb##k;
    PAIRS(DECLV)
#undef DECLV

    // this lane's 32 samples: rows 2*sub, 2*sub+1 contiguous in memory
    {
        const float4* dp = reinterpret_cast<const float4*>(data + (size_t)job * 256 + sub * 32);
        float4 v;
        v = dp[0]; sa0  = v.x; sb0  = v.y; sa1  = v.z; sb1  = v.w;
        v = dp[1]; sa2  = v.x; sb2  = v.y; sa3  = v.z; sb3  = v.w;
        v = dp[2]; sa4  = v.x; sb4  = v.y; sa5  = v.z; sb5  = v.w;
        v = dp[3]; sa6  = v.x; sb6  = v.y; sa7  = v.z; sb7  = v.w;
        v = dp[4]; sa8  = v.x; sb8  = v.y; sa9  = v.z; sb9  = v.w;
        v = dp[5]; sa10 = v.x; sb10 = v.y; sa11 = v.z; sb11 = v.w;
        v = dp[6]; sa12 = v.x; sb12 = v.y; sa13 = v.z; sb13 = v.w;
        v = dp[7]; sa14 = v.x; sb14 = v.y; sa15 = v.z; sb15 = v.w;
    }

    // psf: g = Ey(row) * Ex(col); pairs 0-7 = row 2*sub, pairs 8-15 = row 2*sub+1
    {
        const float r0f = (float)(2 * sub);
        const float ey_a = erff((r0f - y) * CST);
        const float ey_b = erff((r0f + 1.0f - y) * CST);
        const float ey_c = erff((r0f + 2.0f - y) * CST);
        const float eyl0 = 0.5f * (ey_b - ey_a);
        const float eyl1 = 0.5f * (ey_c - ey_b);
        float e0  = erff((0.0f  - x) * CST);
        float e1  = erff((1.0f  - x) * CST);
        float e2  = erff((2.0f  - x) * CST);
        float e3  = erff((3.0f  - x) * CST);
        float e4  = erff((4.0f  - x) * CST);
        float e5  = erff((5.0f  - x) * CST);
        float e6  = erff((6.0f  - x) * CST);
        float e7  = erff((7.0f  - x) * CST);
        float e8  = erff((8.0f  - x) * CST);
        float e9  = erff((9.0f  - x) * CST);
        float e10 = erff((10.0f - x) * CST);
        float e11 = erff((11.0f - x) * CST);
        float e12 = erff((12.0f - x) * CST);
        float e13 = erff((13.0f - x) * CST);
        float e14 = erff((14.0f - x) * CST);
        float e15 = erff((15.0f - x) * CST);
        float e16 = erff((16.0f - x) * CST);
        float x0  = 0.5f * (e1  - e0),  x1  = 0.5f * (e2  - e1);
        float x2  = 0.5f * (e3  - e2),  x3  = 0.5f * (e4  - e3);
        float x4  = 0.5f * (e5  - e4),  x5  = 0.5f * (e6  - e5);
        float x6  = 0.5f * (e7  - e6),  x7  = 0.5f * (e8  - e7);
        float x8  = 0.5f * (e9  - e8),  x9  = 0.5f * (e10 - e9);
        float x10 = 0.5f * (e11 - e10), x11 = 0.5f * (e12 - e11);
        float x12 = 0.5f * (e13 - e12), x13 = 0.5f * (e14 - e13);
        float x14 = 0.5f * (e15 - e14), x15 = 0.5f * (e16 - e15);
        ga0  = eyl0 * x0;  gb0  = eyl0 * x1;
        ga1  = eyl0 * x2;  gb1  = eyl0 * x3;
        ga2  = eyl0 * x4;  gb2  = eyl0 * x5;
        ga3  = eyl0 * x6;  gb3  = eyl0 * x7;
        ga4  = eyl0 * x8;  gb4  = eyl0 * x9;
        ga5  = eyl0 * x10; gb5  = eyl0 * x11;
        ga6  = eyl0 * x12; gb6  = eyl0 * x13;
        ga7  = eyl0 * x14; gb7  = eyl0 * x15;
        ga8  = eyl1 * x0;  gb8  = eyl1 * x1;
        ga9  = eyl1 * x2;  gb9  = eyl1 * x3;
        ga10 = eyl1 * x4;  gb10 = eyl1 * x5;
        ga11 = eyl1 * x6;  gb11 = eyl1 * x7;
        ga12 = eyl1 * x8;  gb12 = eyl1 * x9;
        ga13 = eyl1 * x10; gb13 = eyl1 * x11;
        ga14 = eyl1 * x12; gb14 = eyl1 * x13;
        ga15 = eyl1 * x14; gb15 = eyl1 * x15;
    }

    // S_psf over all 256 pixels (folded -1 terms of df)
    float spsf;
    {
        float spa = 0.0f, spb = 0.0f;
#define ADDG(k) spa += ga##k; spb += gb##k;
        PAIRS(ADDG)
#undef ADDG
        spsf = spa + spb;
        spsf += SWZ(spsf, 0x041F);
        spsf += SWZ(spsf, 0x081F);
        spsf += SWZ(spsf, 0x101F);
    }

    for (int it = 0; it < ITERS; ++it) {
        const float bge = bg + 1e-9f;   // g>=0 guarantees mu>=1e-9 (matches ref clip regime)
        float A0a = 0.0f, A0b = 0.0f;
        float A1a = 0.0f, A1b = 0.0f;
        float A2a = 0.0f, A2b = 0.0f;
#define BODY(k) { \
        float mua = fmaf(I, ga##k, bge); \
        float mub = fmaf(I, gb##k, bge); \
        float ra = __builtin_amdgcn_rcpf(mua); \
        float rb = __builtin_amdgcn_rcpf(mub); \
        float ta = sa##k * ra, tb = sb##k * rb; \
        float ua = ta * ra,    ub = tb * rb; \
        A0a += ua; A0b += ub; \
        float wa = ua * ga##k, wb = ub * gb##k; \
        A1a += wa; A1b += wb; \
        A2a = fmaf(wa, ga##k, A2a); A2b = fmaf(wb, gb##k, A2b); }
        PAIRS(BODY)
#undef BODY
        float U0 = A0a + A0b;
        float U1 = A1a + A1b;
        float U2 = A2a + A2b;
        RED3(U0, U1, U2)

        // identity t = u*mu: sum(smp/mu) = I*U1 + bg*U0, sum(smp/mu * g) = I*U2 + bg*U1
        float a00 = U2 + LAMBDA_;
        float a01 = U1;
        float a11 = U0 + LAMBDA_;
        float b0 = fmaf(I, U2, bg * U1) - spsf;
        float b1 = fmaf(I, U1, bg * U0) - 256.0f;
        float det = fmaf(a00, a11, -(a01 * a01));
        float rd = __builtin_amdgcn_rcpf(det);
        float dI  = fmaf(a11, b0, -(a01 * b1)) * rd;
        float dbg = fmaf(a00, b1, -(a01 * b0)) * rd;
        I  = fminf(fmaxf(I + dI, 1.0f), 1000000.0f);
        bg = fminf(fmaxf(bg + dbg, 1.0f), 1000.0f);
    }

    // epilogue: CRLB + chisq (once; amortized)
    float F00 = 0.0f, F01 = 0.0f, F11 = 0.0f, chis = 0.0f;
#define EPI(k) { \
        float mua = fmaf(I, ga##k, bg); \
        float mub = fmaf(I, gb##k, bg); \
        float inva = __builtin_amdgcn_rcpf(fmaxf(mua, 1e-9f)); \
        float invb = __builtin_amdgcn_rcpf(fmaxf(mub, 1e-9f)); \
        float gia = ga##k * inva, gib = gb##k * invb; \
        F00 = fmaf(gia, ga##k, F00); F00 = fmaf(gib, gb##k, F00); \
        F01 += gia + gib; \
        F11 += inva + invb; \
        float da = sa##k - mua, db = sb##k - mub; \
        chis = fmaf(da * da, __builtin_amdgcn_rcpf(mua + 0.01f), chis); \
        chis = fmaf(db * db, __builtin_amdgcn_rcpf(mub + 0.01f), chis); }
    PAIRS(EPI)
#undef EPI
    {
        float t0 = SWZ(F00, 0x041F), t1 = SWZ(F01, 0x041F), t2 = SWZ(F11, 0x041F), t3 = SWZ(chis, 0x041F);
        F00 += t0; F01 += t1; F11 += t2; chis += t3;
        t0 = SWZ(F00, 0x081F); t1 = SWZ(F01, 0x081F); t2 = SWZ(F11, 0x081F); t3 = SWZ(chis, 0x081F);
        F00 += t0; F01 += t1; F11 += t2; chis += t3;
        t0 = SWZ(F00, 0x101F); t1 = SWZ(F01, 0x101F); t2 = SWZ(F11, 0x101F); t3 = SWZ(chis, 0x101F);
        F00 += t0; F01 += t1; F11 += t2; chis += t3;
    }

    if (sub == 0) {
        float detF = fmaf(F00, F11, -(F01 * F01));
        float rdF = __builtin_amdgcn_rcpf(detF);
        float* o = out + (size_t)job * 5;
        o[0] = I;
        o[1] = bg;
        o[2] = sqrtf(F11 * rdF);
        o[3] = sqrtf(F00 * rdF);
        o[4] = chis;
    }
}

extern "C" void kernel_launch(void* const* d_in, const int* in_sizes, int n_in,
                              void* d_out, int out_size, void* d_ws, size_t ws_size,
                              hipStream_t stream) {
    const float* params = (const float*)d_in[0];
    const float* data   = (const float*)d_in[1];
    float* out = (float*)d_out;
    int nspots = in_sizes[0] / 5;
    int njobs = nspots * PATTERNS;
    long long nthreads = (long long)njobs * 8;
    int blocks = (int)((nthreads + 255) / 256);
    intensity_kernel<<<dim3(blocks), dim3(256), 0, stream>>>(params, data, out, njobs);
}

// Round 8
// 278.713 us; speedup vs baseline: 1.1116x; 1.1116x over previous
//
#include <hip/hip_runtime.h>
#include <math.h>

#define PATTERNS 6
#define ITERS 50
#define LAMBDA_ 100.0f
// 1/(sqrt(2)*SIGMA), SIGMA=1.5
#define CST 0.47140452079103173f

typedef float v2f __attribute__((ext_vector_type(2)));

// xor-swizzle add within 8-lane groups (proven; one DS inst per step)
__device__ __forceinline__ float grpsum8(float x) {
    x += __int_as_float(__builtin_amdgcn_ds_swizzle(__float_as_int(x), 0x041F)); // xor 1
    x += __int_as_float(__builtin_amdgcn_ds_swizzle(__float_as_int(x), 0x081F)); // xor 2
    x += __int_as_float(__builtin_amdgcn_ds_swizzle(__float_as_int(x), 0x101F)); // xor 4
    return x;
}

#define PAIRS(X) X(0) X(1) X(2) X(3) X(4) X(5) X(6) X(7) \
                 X(8) X(9) X(10) X(11) X(12) X(13) X(14) X(15)

// 8 lanes per job: lane `sub` owns rows 2*sub, 2*sub+1 (32 px, register-resident).
// R6 body (6 ops/px, gg hoist) + sched_barrier fences bounding the scheduler's
// register-pressure window + uncapped arch-VGPR budget (launch_bounds min-waves=2)
// so state stays in ARCH VGPRs (no v_accvgpr_read copy traffic on every use).
__global__ __launch_bounds__(256, 2) void intensity_kernel(
    const float* __restrict__ params,
    const float* __restrict__ data,
    float* __restrict__ out,
    int njobs)
{
    const int tid = blockIdx.x * 256 + threadIdx.x;
    const int job = tid >> 3;
    const int sub = tid & 7;
    if (job >= njobs) return;
    const int spot = job / PATTERNS;

    const float x = params[spot * 5 + 0];
    const float y = params[spot * 5 + 1];
    float I = params[spot * 5 + 4] * (1.0f / PATTERNS);
    float bg = 0.0f;

#define DECLV(k) v2f g##k, gg##k, s##k;
    PAIRS(DECLV)
#undef DECLV

    // this lane's 32 samples: rows 2*sub, 2*sub+1 contiguous in memory
    {
        const float4* dp = reinterpret_cast<const float4*>(data + (size_t)job * 256 + sub * 32);
        float4 v;
        v = dp[0]; s0  = (v2f){v.x, v.y}; s1  = (v2f){v.z, v.w};
        v = dp[1]; s2  = (v2f){v.x, v.y}; s3  = (v2f){v.z, v.w};
        v = dp[2]; s4  = (v2f){v.x, v.y}; s5  = (v2f){v.z, v.w};
        v = dp[3]; s6  = (v2f){v.x, v.y}; s7  = (v2f){v.z, v.w};
        v = dp[4]; s8  = (v2f){v.x, v.y}; s9  = (v2f){v.z, v.w};
        v = dp[5]; s10 = (v2f){v.x, v.y}; s11 = (v2f){v.z, v.w};
        v = dp[6]; s12 = (v2f){v.x, v.y}; s13 = (v2f){v.z, v.w};
        v = dp[7]; s14 = (v2f){v.x, v.y}; s15 = (v2f){v.z, v.w};
    }

    // psf: g = Ey(row) * Ex(col); rows 2*sub (pairs 0-7), 2*sub+1 (pairs 8-15)
    {
        const float r0f = (float)(2 * sub);
        const float ey_a = erff((r0f - y) * CST);
        const float ey_b = erff((r0f + 1.0f - y) * CST);
        const float ey_c = erff((r0f + 2.0f - y) * CST);
        const float eyl0 = 0.5f * (ey_b - ey_a);
        const float eyl1 = 0.5f * (ey_c - ey_b);
        float e0  = erff((0.0f  - x) * CST);
        float e1  = erff((1.0f  - x) * CST);
        float e2  = erff((2.0f  - x) * CST);
        float e3  = erff((3.0f  - x) * CST);
        float e4  = erff((4.0f  - x) * CST);
        float e5  = erff((5.0f  - x) * CST);
        float e6  = erff((6.0f  - x) * CST);
        float e7  = erff((7.0f  - x) * CST);
        float e8  = erff((8.0f  - x) * CST);
        float e9  = erff((9.0f  - x) * CST);
        float e10 = erff((10.0f - x) * CST);
        float e11 = erff((11.0f - x) * CST);
        float e12 = erff((12.0f - x) * CST);
        float e13 = erff((13.0f - x) * CST);
        float e14 = erff((14.0f - x) * CST);
        float e15 = erff((15.0f - x) * CST);
        float e16 = erff((16.0f - x) * CST);
        v2f ex0 = (v2f){0.5f * (e1  - e0),  0.5f * (e2  - e1)};
        v2f ex1 = (v2f){0.5f * (e3  - e2),  0.5f * (e4  - e3)};
        v2f ex2 = (v2f){0.5f * (e5  - e4),  0.5f * (e6  - e5)};
        v2f ex3 = (v2f){0.5f * (e7  - e6),  0.5f * (e8  - e7)};
        v2f ex4 = (v2f){0.5f * (e9  - e8),  0.5f * (e10 - e9)};
        v2f ex5 = (v2f){0.5f * (e11 - e10), 0.5f * (e12 - e11)};
        v2f ex6 = (v2f){0.5f * (e13 - e12), 0.5f * (e14 - e13)};
        v2f ex7 = (v2f){0.5f * (e15 - e14), 0.5f * (e16 - e15)};
        g0  = eyl0 * ex0; g1  = eyl0 * ex1; g2  = eyl0 * ex2; g3  = eyl0 * ex3;
        g4  = eyl0 * ex4; g5  = eyl0 * ex5; g6  = eyl0 * ex6; g7  = eyl0 * ex7;
        g8  = eyl1 * ex0; g9  = eyl1 * ex1; g10 = eyl1 * ex2; g11 = eyl1 * ex3;
        g12 = eyl1 * ex4; g13 = eyl1 * ex5; g14 = eyl1 * ex6; g15 = eyl1 * ex7;
#define MKGG(k) gg##k = g##k * g##k;
        PAIRS(MKGG)
#undef MKGG
    }

    // S_psf over all 256 pixels (folded -1 terms of df)
    float spsf;
    {
        v2f sp = (v2f){0.0f, 0.0f};
#define ADDG(k) sp += g##k;
        PAIRS(ADDG)
#undef ADDG
        spsf = grpsum8(sp[0] + sp[1]);
    }

    for (int it = 0; it < ITERS; ++it) {
        const float bge = bg + 1e-9f;   // g>=0 guarantees mu>=1e-9 (matches ref clip regime)
        v2f A0 = (v2f){0.0f, 0.0f}, A1 = (v2f){0.0f, 0.0f}, A2 = (v2f){0.0f, 0.0f};
#define BODY(k) { \
        v2f mu = g##k * I + bge; \
        v2f r; \
        r[0] = __builtin_amdgcn_rcpf(mu[0]); \
        r[1] = __builtin_amdgcn_rcpf(mu[1]); \
        v2f u  = (s##k * r) * r; \
        A0 += u; \
        A1 = u * g##k  + A1; \
        A2 = u * gg##k + A2; }
        BODY(0) BODY(1) BODY(2) BODY(3)
        __builtin_amdgcn_sched_barrier(0);
        BODY(4) BODY(5) BODY(6) BODY(7)
        __builtin_amdgcn_sched_barrier(0);
        BODY(8) BODY(9) BODY(10) BODY(11)
        __builtin_amdgcn_sched_barrier(0);
        BODY(12) BODY(13) BODY(14) BODY(15)
        __builtin_amdgcn_sched_barrier(0);
#undef BODY
        float U0 = grpsum8(A0[0] + A0[1]);
        float U1 = grpsum8(A1[0] + A1[1]);
        float U2 = grpsum8(A2[0] + A2[1]);

        // identity t = u*mu: sum(smp/mu) = I*U1 + bg*U0, sum(smp/mu * g) = I*U2 + bg*U1
        float a00 = U2 + LAMBDA_;
        float a01 = U1;
        float a11 = U0 + LAMBDA_;
        float b0 = fmaf(I, U2, bg * U1) - spsf;
        float b1 = fmaf(I, U1, bg * U0) - 256.0f;
        float det = fmaf(a00, a11, -(a01 * a01));
        float rd = __builtin_amdgcn_rcpf(det);
        float dI  = fmaf(a11, b0, -(a01 * b1)) * rd;
        float dbg = fmaf(a00, b1, -(a01 * b0)) * rd;
        I  = fminf(fmaxf(I + dI, 1.0f), 1000000.0f);
        bg = fminf(fmaxf(bg + dbg, 1.0f), 1000.0f);
    }

    // epilogue: CRLB + chisq (once; amortized)
    float F00 = 0.0f, F01 = 0.0f, F11 = 0.0f, chis = 0.0f;
#define EPI(k) { \
        v2f mu = g##k * I + bg; \
        v2f inv; \
        inv[0] = __builtin_amdgcn_rcpf(fmaxf(mu[0], 1e-9f)); \
        inv[1] = __builtin_amdgcn_rcpf(fmaxf(mu[1], 1e-9f)); \
        v2f d  = s##k - mu; \
        v2f c; \
        c[0] = d[0] * d[0] * __builtin_amdgcn_rcpf(mu[0] + 0.01f); \
        c[1] = d[1] * d[1] * __builtin_amdgcn_rcpf(mu[1] + 0.01f); \
        F00 += gg##k[0] * inv[0] + gg##k[1] * inv[1]; \
        F01 += g##k[0]  * inv[0] + g##k[1]  * inv[1]; \
        F11 += inv[0] + inv[1]; \
        chis += c[0] + c[1]; }
    PAIRS(EPI)
#undef EPI
    F00  = grpsum8(F00);
    F01  = grpsum8(F01);
    F11  = grpsum8(F11);
    chis = grpsum8(chis);

    if (sub == 0) {
        float detF = fmaf(F00, F11, -(F01 * F01));
        float rdF = __builtin_amdgcn_rcpf(detF);
        float* o = out + (size_t)job * 5;
        o[0] = I;
        o[1] = bg;
        o[2] = sqrtf(F11 * rdF);
        o[3] = sqrtf(F00 * rdF);
        o[4] = chis;
    }
}

extern "C" void kernel_launch(void* const* d_in, const int* in_sizes, int n_in,
                              void* d_out, int out_size, void* d_ws, size_t ws_size,
                              hipStream_t stream) {
    const float* params = (const float*)d_in[0];
    const float* data   = (const float*)d_in[1];
    float* out = (float*)d_out;
    int nspots = in_sizes[0] / 5;
    int njobs = nspots * PATTERNS;
    long long nthreads = (long long)njobs * 8;
    int blocks = (int)((nthreads + 255) / 256);
    intensity_kernel<<<dim3(blocks), dim3(256), 0, stream>>>(params, data, out, njobs);
}